// Round 22
// baseline (287.891 us; speedup 1.0000x reference)
//
#include <hip/hip_runtime.h>
#include <hip/hip_bf16.h>
#include <math.h>

#define Bv 2
#define Nv 2048
#define Cv 128
#define Dv 256
#define PHv 64
#define AHv 1024
#define Kv 16
#define NSAMP (Bv*Nv*Kv)   // 65536

typedef unsigned short ushortt;
typedef unsigned char u8;
typedef __attribute__((ext_vector_type(8))) short bf16x8;
typedef __attribute__((ext_vector_type(4))) float f32x4;

__device__ __forceinline__ float bf2f(ushortt h){
  union { unsigned int u; float f; } v; v.u = ((unsigned int)h) << 16; return v.f;
}
__device__ __forceinline__ ushortt f2bf(float f){
  union { unsigned int u; float f; } v; v.f = f;
  unsigned int r = v.u + 0x7FFFu + ((v.u >> 16) & 1u);
  return (ushortt)(r >> 16);
}
// f32 -> fp8 e4m3fn (OCP), RNE, clamp to 448, FTZ subnormals
__device__ __forceinline__ u8 f2fp8(float f){
  union { float f; unsigned int u; } v; v.f = f;
  unsigned int s = (v.u >> 24) & 0x80u;
  unsigned int a = v.u & 0x7FFFFFFFu;
  if (a > 0x43E00000u) a = 0x43E00000u;           // 448.0
  unsigned int r = a + 0x7FFFFu + ((a >> 20) & 1u);
  int e = (int)((r >> 23) & 0xFF) - 120;          // -127 + 7
  unsigned int m = (r >> 20) & 7u;
  if (e <= 0) return (u8)s;
  return (u8)(s | ((unsigned)e << 3) | m);
}
// non-negative fast path (post-relu): same result as f2fp8 for f >= 0
__device__ __forceinline__ u8 f2fp8u(float f){
  union { float f; unsigned int u; } v; v.f = f;
  unsigned int a = v.u;
  if (a > 0x43E00000u) a = 0x43E00000u;
  unsigned int r = a + 0x7FFFFu + ((a >> 20) & 1u);
  unsigned int out = (r >> 20) - 960u;            // ((e)<<3)|m
  return (u8)(r < 0x3C800000u ? 0u : out);
}
// fp8 e4m3fn -> f32 (encoder is FTZ, never emits subnormals/NaN)
__device__ __forceinline__ float fp82f(u8 x){
  unsigned int em = x & 0x7Fu;
  union { unsigned int u; float f; } v;
  v.u = ((unsigned int)(x & 0x80u) << 24) | ((em << 20) + (120u << 23));
  return em < 8u ? 0.f : v.f;
}

__device__ __forceinline__ void gload16(const void* g, void* l){
  __builtin_amdgcn_global_load_lds(
      (const __attribute__((address_space(1))) unsigned int*)g,
      (__attribute__((address_space(3))) unsigned int*)l, 16, 0, 0);
}

// ---------------- prep: weight packs / casts + xcat (grid-split) ----------------
__global__ __launch_bounds__(256) void prep_kernel(
    const float* __restrict__ wk, const float* __restrict__ wq,
    const float* __restrict__ wv, const float* __restrict__ endw,
    const float* __restrict__ mw1, const float* __restrict__ mw2,
    const float* __restrict__ mwsc, const float* __restrict__ aw2,
    const float* __restrict__ pw2,
    const float* __restrict__ key, const float* __restrict__ query,
    ushortt* __restrict__ wA16, ushortt* __restrict__ wB16, ushortt* __restrict__ wv16,
    float* __restrict__ endwT, u8* __restrict__ w2f8, ushortt* __restrict__ pw2R,
    ushortt* __restrict__ hx16)
{
  __shared__ float xs[256*33];
  int t = threadIdx.x;
  if (blockIdx.x < 128){
    int tile = blockIdx.x & 63, b = blockIdx.x >> 6;
    int n0 = tile*32;
    for (int e = t; e < 256*32; e += 256){
      int c = e >> 5, nn = e & 31;
      xs[c*33+nn] = (c < 128) ? key[(size_t)(b*128+c)*Nv + n0+nn]
                              : query[(size_t)(b*128+(c-128))*Nv + n0+nn];
    }
    __syncthreads();
    int nn = t & 31, cg = t >> 5;    // cg 0..7
    size_t s = (size_t)b*Nv + n0 + nn;
    __align__(16) ushortt tmp[32];
    #pragma unroll
    for (int cc = 0; cc < 32; cc++) tmp[cc] = f2bf(xs[(cg*32+cc)*33 + nn]);
    uint4* dst = (uint4*)&hx16[s*384 + 128 + cg*32];
    #pragma unroll
    for (int q = 0; q < 4; q++) dst[q] = ((uint4*)tmp)[q];
    return;
  }
  int tid = (blockIdx.x-128)*256 + t;
  int stride = (gridDim.x-128)*256;
  for (int i = tid; i < 768*256; i += stride){
    int r = i >> 8, c = i & 255;
    float v;
    if (r < 128) v = mw1[r*256 + c];
    else if (r < 384) v = (c < 128) ? wk[(r-128)*128 + c] : 0.f;
    else if (r < 640) v = (c >= 128) ? wq[(r-384)*128 + (c-128)] : 0.f;
    else v = 0.f;
    wA16[i] = f2bf(v);
  }
  for (int i = tid; i < 128*384; i += stride){
    int r = i / 384, c = i - r*384;
    float v = (c < 128) ? mw2[r*128 + c] : mwsc[r*256 + (c-128)];
    wB16[i] = f2bf(v);
  }
  for (int i = tid; i < 256*128; i += stride) wv16[i] = f2bf(wv[i]);
  for (int i = tid; i < 128*256; i += stride){ int co = i>>8, d = i&255; endwT[d*128+co] = endw[i]; }
  for (int i = tid; i < 256*1024; i += stride) w2f8[i] = f2fp8(aw2[i]*256.f);
  for (int i = tid; i < 256*64; i += stride) pw2R[i] = f2bf(pw2[i]);
}

// ---------------- gemmA: [4096 x 768 x K=256] -> h(relu,bf16), kT16, qT16 ----------------
__global__ __launch_bounds__(512) void gemmA_kernel(
    ushortt* __restrict__ hx16, const ushortt* __restrict__ wA16,
    const float* __restrict__ mb1, const float* __restrict__ bk, const float* __restrict__ bq,
    ushortt* __restrict__ kT, ushortt* __restrict__ qT)
{
  __shared__ ushortt As[128*64];
  __shared__ ushortt Bs[256*64];
  int t = threadIdx.x;
  int w = t >> 6, l = t & 63;
  int lr = l & 15, g4 = l >> 4;
  int wm = w >> 2, wn = w & 3;
  int s0 = blockIdx.x*128, n0 = blockIdx.y*256;

  f32x4 acc[4][4];
  #pragma unroll
  for (int i=0;i<4;i++) for (int j=0;j<4;j++) acc[i][j] = (f32x4){0.f,0.f,0.f,0.f};

  for (int kt = 0; kt < 4; kt++){
    int k0 = kt*64;
    __syncthreads();
    #pragma unroll
    for (int i = 0; i < 2; i++){
      int c = t + i*512;
      int r = c >> 3, db = (c & 7)*16;
      const ushortt* src = hx16 + (size_t)(s0+r)*384 + 128 + k0 + ((db ^ ((r&7)<<4))>>1);
      gload16(src, As + c*8);
    }
    #pragma unroll
    for (int i = 0; i < 4; i++){
      int c = t + i*512;
      int r = c >> 3, db = (c & 7)*16;
      const ushortt* src = wA16 + (size_t)(n0+r)*256 + k0 + ((db ^ ((r&7)<<4))>>1);
      gload16(src, Bs + c*8);
    }
    __syncthreads();
    #pragma unroll
    for (int kk = 0; kk < 2; kk++){
      int kb = kk*64 + g4*16;
      bf16x8 af[4];
      #pragma unroll
      for (int mi = 0; mi < 4; mi++){
        int row = wm*64 + mi*16 + lr;
        af[mi] = *(const bf16x8*)((const char*)As + row*128 + (kb ^ ((row&7)<<4)));
      }
      #pragma unroll
      for (int ni = 0; ni < 4; ni++){
        int row = wn*64 + ni*16 + lr;
        bf16x8 bfr = *(const bf16x8*)((const char*)Bs + row*128 + (kb ^ ((row&7)<<4)));
        #pragma unroll
        for (int mi = 0; mi < 4; mi++)
          acc[mi][ni] = __builtin_amdgcn_mfma_f32_16x16x32_bf16(af[mi], bfr, acc[mi][ni], 0,0,0);
      }
    }
  }
  #pragma unroll
  for (int ni = 0; ni < 4; ni++){
    int col = n0 + wn*64 + ni*16 + lr;
    if (col < 128){
      float bias = mb1[col];
      #pragma unroll
      for (int mi = 0; mi < 4; mi++){
        int rbase = s0 + wm*64 + mi*16 + g4*4;
        #pragma unroll
        for (int r = 0; r < 4; r++){
          float v = acc[mi][ni][r] + bias;
          v = v > 0.f ? v : 0.f;
          hx16[(size_t)(rbase+r)*384 + col] = f2bf(v);
        }
      }
    } else if (col < 384){
      float bias = bk[col-128];
      #pragma unroll
      for (int mi = 0; mi < 4; mi++){
        int rbase = s0 + wm*64 + mi*16 + g4*4;
        #pragma unroll
        for (int r = 0; r < 4; r++)
          kT[(size_t)(rbase+r)*256 + (col-128)] = f2bf(acc[mi][ni][r] + bias);
      }
    } else if (col < 640){
      float bias = bq[col-384];
      #pragma unroll
      for (int mi = 0; mi < 4; mi++){
        int rbase = s0 + wm*64 + mi*16 + g4*4;
        #pragma unroll
        for (int r = 0; r < 4; r++)
          qT[(size_t)(rbase+r)*256 + (col-384)] = f2bf(acc[mi][ni][r] + bias);
      }
    }
  }
}

// ---------------- gemmBC: valueT = hx @ wB^T + b ; vT16 = value16 @ wv^T + bv (fused) ----------------
__global__ __launch_bounds__(512) void gemmBC_kernel(
    const ushortt* __restrict__ hx16, const ushortt* __restrict__ wB16,
    const float* __restrict__ mb2, const float* __restrict__ mbsc,
    const ushortt* __restrict__ wv16, const float* __restrict__ bv,
    float* __restrict__ valueT, ushortt* __restrict__ vT)
{
  __shared__ char arena[65536];
  ushortt* As = (ushortt*)arena;
  ushortt* Bs = (ushortt*)(arena + 16384);
  ushortt* Ws = (ushortt*)arena;
  char*    Vs = arena + 32768;
  int t = threadIdx.x;
  int w = t >> 6, l = t & 63;
  int lr = l & 15, g4 = l >> 4;
  int wm = w >> 2, wn = w & 3;
  int s0 = blockIdx.x*128;

  {
    f32x4 acc[4][2];
    #pragma unroll
    for (int i=0;i<4;i++) for (int j=0;j<2;j++) acc[i][j] = (f32x4){0.f,0.f,0.f,0.f};

    for (int kt = 0; kt < 6; kt++){
      int k0 = kt*64;
      __syncthreads();
      #pragma unroll
      for (int i = 0; i < 2; i++){
        int c = t + i*512;
        int r = c >> 3, db = (c & 7)*16;
        const ushortt* src = hx16 + (size_t)(s0+r)*384 + k0 + ((db ^ ((r&7)<<4))>>1);
        gload16(src, As + c*8);
      }
      #pragma unroll
      for (int i = 0; i < 2; i++){
        int c = t + i*512;
        int r = c >> 3, db = (c & 7)*16;
        const ushortt* src = wB16 + (size_t)r*384 + k0 + ((db ^ ((r&7)<<4))>>1);
        gload16(src, Bs + c*8);
      }
      __syncthreads();
      #pragma unroll
      for (int kk = 0; kk < 2; kk++){
        int kb = kk*64 + g4*16;
        bf16x8 af[4];
        #pragma unroll
        for (int mi = 0; mi < 4; mi++){
          int row = wm*64 + mi*16 + lr;
          af[mi] = *(const bf16x8*)((const char*)As + row*128 + (kb ^ ((row&7)<<4)));
        }
        #pragma unroll
        for (int ni = 0; ni < 2; ni++){
          int row = wn*32 + ni*16 + lr;
          bf16x8 bfr = *(const bf16x8*)((const char*)Bs + row*128 + (kb ^ ((row&7)<<4)));
          #pragma unroll
          for (int mi = 0; mi < 4; mi++)
            acc[mi][ni] = __builtin_amdgcn_mfma_f32_16x16x32_bf16(af[mi], bfr, acc[mi][ni], 0,0,0);
        }
      }
    }
    #pragma unroll
    for (int ni = 0; ni < 2; ni++){
      int col = wn*32 + ni*16 + lr;
      float bias = mb2[col] + mbsc[col];
      #pragma unroll
      for (int mi = 0; mi < 4; mi++){
        int rloc = wm*64 + mi*16 + g4*4;
        #pragma unroll
        for (int r = 0; r < 4; r++){
          float v = acc[mi][ni][r] + bias;
          valueT[(size_t)(s0+rloc+r)*128 + col] = v;
          int row = rloc + r;
          *(ushortt*)(Vs + row*256 + ((col*2) ^ ((row&7)<<4))) = f2bf(v);
        }
      }
    }
  }
  {
    f32x4 acc2[4][4];
    #pragma unroll
    for (int i=0;i<4;i++) for (int j=0;j<4;j++) acc2[i][j] = (f32x4){0.f,0.f,0.f,0.f};

    for (int kt = 0; kt < 2; kt++){
      int k0 = kt*64;
      __syncthreads();
      #pragma unroll
      for (int i = 0; i < 4; i++){
        int c = t + i*512;
        int r = c >> 3, db = (c & 7)*16;
        const ushortt* src = wv16 + (size_t)r*128 + k0 + ((db ^ ((r&7)<<4))>>1);
        gload16(src, Ws + c*8);
      }
      __syncthreads();
      #pragma unroll
      for (int kk = 0; kk < 2; kk++){
        int kb = kk*64 + g4*16;
        bf16x8 af[4];
        #pragma unroll
        for (int mi = 0; mi < 4; mi++){
          int row = wm*64 + mi*16 + lr;
          af[mi] = *(const bf16x8*)(Vs + row*256 + ((kt*128 + kb) ^ ((row&7)<<4)));
        }
        #pragma unroll
        for (int ni = 0; ni < 4; ni++){
          int row = wn*64 + ni*16 + lr;
          bf16x8 bfr = *(const bf16x8*)((const char*)Ws + row*128 + (kb ^ ((row&7)<<4)));
          #pragma unroll
          for (int mi = 0; mi < 4; mi++)
            acc2[mi][ni] = __builtin_amdgcn_mfma_f32_16x16x32_bf16(af[mi], bfr, acc2[mi][ni], 0,0,0);
        }
      }
    }
    #pragma unroll
    for (int ni = 0; ni < 4; ni++){
      int col = wn*64 + ni*16 + lr;
      float bias = bv[col];
      #pragma unroll
      for (int mi = 0; mi < 4; mi++){
        int rbase = s0 + wm*64 + mi*16 + g4*4;
        #pragma unroll
        for (int r = 0; r < 4; r++)
          vT[(size_t)(rbase+r)*256 + col] = f2bf(acc2[mi][ni][r] + bias);
      }
    }
  }
}

// ---------------- KNN: wave-per-point, pure shfl ----------------
__global__ __launch_bounds__(256) void knn_kernel(const float* __restrict__ pos, int* __restrict__ idx)
{
  int t = threadIdx.x;
  int w = t >> 6, l = t & 63;
  int p = blockIdx.x*4 + w;
  int i = p & (Nv-1), b = p >> 11;
  const float* px = pos + (size_t)b*3*Nv;
  float pix = px[i], piy = px[Nv+i], piz = px[2*Nv+i];
  float sqi = pix*pix + piy*piy + piz*piz;
  float ds[32];
  #pragma unroll
  for (int jj = 0; jj < 32; jj++){
    int j = jj*64 + l;
    float qx = px[j], qy = px[Nv+j], qz = px[2*Nv+j];
    float sqj = qx*qx + qy*qy + qz*qz;
    float dot = pix*qx + piy*qy + piz*qz;
    ds[jj] = (sqi + sqj) - 2.0f*dot;
  }
  #pragma unroll 1
  for (int it = 0; it < 16; it++){
    float bv = 3.4e38f; int bj = 0x7FFFFFFF;
    #pragma unroll
    for (int jj = 0; jj < 32; jj++){
      int j = jj*64 + l;
      bool c = ds[jj] < bv;
      bv = c ? ds[jj] : bv;
      bj = c ? j : bj;
    }
    #pragma unroll
    for (int off = 32; off; off >>= 1){
      float ov = __shfl_xor(bv, off);
      int oj = __shfl_xor(bj, off);
      if (ov < bv || (ov == bv && oj < bj)){ bv = ov; bj = oj; }
    }
    if (l == 0) idx[(size_t)p*16 + it] = bj;
    #pragma unroll
    for (int jj = 0; jj < 32; jj++){
      if (jj*64 + l == bj) ds[jj] = 3.4e38f;
    }
  }
}

// ---------------- pos-BN stats ----------------
__global__ __launch_bounds__(256) void bn1_stats(const float* __restrict__ pos,
    const int* __restrict__ idx, float* __restrict__ rstat)
{
  int tid = blockIdx.x*256 + threadIdx.x;
  int stride = gridDim.x*256;
  float s[9] = {0,0,0,0,0,0,0,0,0};
  for (int e = tid; e < NSAMP; e += stride){
    int b = e >> 15;
    int rem = e & 32767;
    int n = rem >> 4, k = rem & 15;
    int j = idx[(size_t)(b*Nv+n)*16 + k];
    const float* px = pos + (size_t)b*3*Nv;
    float rx = px[n]-px[j], ry = px[Nv+n]-px[Nv+j], rz = px[2*Nv+n]-px[2*Nv+j];
    s[0]+=rx; s[1]+=ry; s[2]+=rz;
    s[3]+=rx*rx; s[4]+=rx*ry; s[5]+=rx*rz; s[6]+=ry*ry; s[7]+=ry*rz; s[8]+=rz*rz;
  }
  for (int off=32; off; off>>=1)
    for (int q=0;q<9;q++) s[q] += __shfl_xor(s[q], off);
  if ((threadIdx.x & 63) == 0)
    for (int q=0;q<9;q++) atomicAdd(&rstat[q], s[q]);
}

// ---------------- Hpos = relu(BN(W1 r)) -> bf16 [65536 x 64]; BN fold inlined ----------------
__global__ __launch_bounds__(256) void hpos_kernel(
    const float* __restrict__ pos, const int* __restrict__ idx,
    const float* __restrict__ rstat, const float* __restrict__ pw1,
    const float* __restrict__ pg, const float* __restrict__ pbeta,
    ushortt* __restrict__ hposR)
{
  __shared__ float w1s[192];
  __shared__ float b1s[64];
  int t = threadIdx.x;
  if (t < 64){
    float inv = 1.0f/(float)NSAMP;
    float mux = rstat[0]*inv, muy = rstat[1]*inv, muz = rstat[2]*inv;
    float xx = rstat[3]*inv, xy = rstat[4]*inv, xz = rstat[5]*inv;
    float yy = rstat[6]*inv, yz = rstat[7]*inv, zz = rstat[8]*inv;
    float w0 = pw1[t*3], w1 = pw1[t*3+1], w2 = pw1[t*3+2];
    float dot = w0*mux + w1*muy + w2*muz;
    float quad = w0*w0*xx + w1*w1*yy + w2*w2*zz + 2.f*(w0*w1*xy + w0*w2*xz + w1*w2*yz);
    float var = quad - dot*dot;
    float sc = pg[t] * rsqrtf(var + 1e-5f);
    w1s[t*3]   = w0*sc;
    w1s[t*3+1] = w1*sc;
    w1s[t*3+2] = w2*sc;
    b1s[t] = pbeta[t] - dot*sc;
  }
  __syncthreads();
  int s = blockIdx.x*32 + (t>>3);
  int c0 = (t&7)*8;
  int ptv = s >> 4;
  int n = ptv & (Nv-1), b = ptv >> 11;
  int j = idx[s];
  const float* px = pos + (size_t)b*3*Nv;
  float rx = px[n]-px[j], ry = px[Nv+n]-px[Nv+j], rz = px[2*Nv+n]-px[2*Nv+j];
  ushortt outv[8];
  #pragma unroll
  for (int e = 0; e < 8; e++){
    int c = c0+e;
    float v = b1s[c] + w1s[c*3]*rx + w1s[c*3+1]*ry + w1s[c*3+2]*rz;
    outv[e] = f2bf(v > 0.f ? v : 0.f);
  }
  *(uint4*)&hposR[(size_t)s*64 + c0] = *(uint4*)outv;
}

// ---------------- GEMM0: pe = Hpos @ pw2^T + pb2; epilogue: U8, val8, mu ----------------
__global__ __launch_bounds__(512) void gemm0_kernel(
    const ushortt* __restrict__ hposR, const ushortt* __restrict__ pw2R,
    const float* __restrict__ pb2, const int* __restrict__ idx,
    const ushortt* __restrict__ qT, const ushortt* __restrict__ kT, const ushortt* __restrict__ vT,
    u8* __restrict__ U8, u8* __restrict__ val8, float* __restrict__ mu_sum)
{
  __shared__ ushortt As[128*64];
  __shared__ ushortt Bs[256*64];   // reused as repack arena after MFMA
  __shared__ float mured[8*256];
  int t = threadIdx.x;
  int w = t >> 6, l = t & 63;
  int lr = l & 15, g4 = l >> 4;
  int wm = w >> 2, wn = w & 3;
  int s0 = blockIdx.x*128;

  #pragma unroll
  for (int i = 0; i < 2; i++){
    int c = t + i*512;
    int r = c >> 3, db = (c & 7)*16;
    const ushortt* src = hposR + (size_t)(s0+r)*64 + ((db ^ ((r&7)<<4))>>1);
    gload16(src, As + c*8);
  }
  #pragma unroll
  for (int i = 0; i < 4; i++){
    int c = t + i*512;
    int r = c >> 3, db = (c & 7)*16;
    const ushortt* src = pw2R + (size_t)r*64 + ((db ^ ((r&7)<<4))>>1);
    gload16(src, Bs + c*8);
  }
  __syncthreads();

  f32x4 acc[4][4];
  #pragma unroll
  for (int i=0;i<4;i++) for (int j=0;j<4;j++) acc[i][j] = (f32x4){0.f,0.f,0.f,0.f};
  #pragma unroll
  for (int kk = 0; kk < 2; kk++){
    int kb = kk*64 + g4*16;
    bf16x8 af[4];
    #pragma unroll
    for (int mi = 0; mi < 4; mi++){
      int row = wm*64 + mi*16 + lr;
      af[mi] = *(const bf16x8*)((const char*)As + row*128 + (kb ^ ((row&7)<<4)));
    }
    #pragma unroll
    for (int ni = 0; ni < 4; ni++){
      int row = wn*64 + ni*16 + lr;
      bf16x8 bfr = *(const bf16x8*)((const char*)Bs + row*128 + (kb ^ ((row&7)<<4)));
      #pragma unroll
      for (int mi = 0; mi < 4; mi++)
        acc[mi][ni] = __builtin_amdgcn_mfma_f32_16x16x32_bf16(af[mi], bfr, acc[mi][ni], 0,0,0);
    }
  }
  __syncthreads();   // Bs dead; reuse as repack arena
  u8* rep = (u8*)Bs; // 128 x 256 fp8 = 32 KB

  u8 v8loc[64];      // per-thread val8 stash (statically indexed)
  float musum[4] = {0.f,0.f,0.f,0.f};
  __align__(16) float pb2v[4];
  #pragma unroll
  for (int ni = 0; ni < 4; ni++) pb2v[ni] = pb2[wn*64 + ni*16 + lr];
  #pragma unroll
  for (int mi = 0; mi < 4; mi++){
    #pragma unroll
    for (int r4 = 0; r4 < 4; r4++){
      int sloc = wm*64 + mi*16 + g4*4 + r4;
      int s = s0 + sloc;
      int ptv = s >> 4;
      int b = s >> 15;
      int j = idx[s];
      const ushortt* krow = kT + (size_t)(b*Nv + j)*256;
      const ushortt* qrow = qT + (size_t)ptv*256;
      const ushortt* vrow = vT + (size_t)ptv*256;
      #pragma unroll
      for (int ni = 0; ni < 4; ni++){
        int d = wn*64 + ni*16 + lr;
        float pe = acc[mi][ni][r4] + pb2v[ni];
        float u = bf2f(qrow[d]) - bf2f(krow[d]) + pe;
        rep[sloc*256 + d] = f2fp8(16.f*u);
        v8loc[(mi*4+r4)*4 + ni] = f2fp8(16.f*(bf2f(vrow[d]) + pe));
        musum[ni] += u;
      }
    }
  }
  #pragma unroll
  for (int ni = 0; ni < 4; ni++)
    mured[(wm*4+g4)*256 + wn*64 + ni*16 + lr] = musum[ni];
  __syncthreads();
  // coalesced U8 store (linear)
  #pragma unroll
  for (int i = 0; i < 4; i++){
    int e = t + i*512;
    int row = e >> 4, off = (e & 15)*16;
    *(uint4*)&U8[(size_t)(s0+row)*256 + off] = *(const uint4*)(rep + e*16);
  }
  __syncthreads();   // U8 stores read rep; now safe to overwrite
  // repack val8 into rep
  #pragma unroll
  for (int mi = 0; mi < 4; mi++){
    #pragma unroll
    for (int r4 = 0; r4 < 4; r4++){
      int sloc = wm*64 + mi*16 + g4*4 + r4;
      #pragma unroll
      for (int ni = 0; ni < 4; ni++){
        int d = wn*64 + ni*16 + lr;
        rep[sloc*256 + d] = v8loc[(mi*4+r4)*4 + ni];
      }
    }
  }
  __syncthreads();
  // coalesced val8 store (linear)
  #pragma unroll
  for (int i = 0; i < 4; i++){
    int e = t + i*512;
    int row = e >> 4, off = (e & 15)*16;
    *(uint4*)&val8[(size_t)(s0+row)*256 + off] = *(const uint4*)(rep + e*16);
  }
  if (t < 256){
    float ssum = 0.f;
    #pragma unroll
    for (int q = 0; q < 8; q++) ssum += mured[q*256 + t];
    atomicAdd(&mu_sum[t], ssum);
  }
}

// ---------------- M partials (fp8: consumes U8 = fp8(16u); Mpart = acc/256) ----------------
__global__ __launch_bounds__(512) void mm_kernel(const u8* __restrict__ U8,
                                                 ushortt* __restrict__ Mpart)
{
  __shared__ u8 Ut[256*64];   // 16 KB fp8, [c][s], 64B pitch, XOR swizzle (row&7)<<3
  int t = threadIdx.x;
  int w = t >> 6, l = t & 63;
  int lr = l & 15, g4 = l >> 4;
  int wm = w >> 2, wn = w & 3;
  int c_my = ((w & 3)*64 + l);
  int sg = w >> 2;
  int blk = blockIdx.x;
  int sstart = blk*256;

  f32x4 acc[8][4];
  #pragma unroll
  for (int i=0;i<8;i++) for (int j=0;j<4;j++) acc[i][j] = (f32x4){0.f,0.f,0.f,0.f};

  for (int st = 0; st < 4; st++){
    int sb = sstart + st*64;
    __syncthreads();
    #pragma unroll
    for (int g = 0; g < 4; g++){
      int s8 = sg*32 + g*8;
      unsigned int p0 = 0, p1 = 0;
      #pragma unroll
      for (int e = 0; e < 4; e++)
        p0 |= (unsigned int)U8[(size_t)(sb + s8 + e)*256 + c_my] << (8*e);
      #pragma unroll
      for (int e = 0; e < 4; e++)
        p1 |= (unsigned int)U8[(size_t)(sb + s8 + 4 + e)*256 + c_my] << (8*e);
      *(uint2*)(Ut + c_my*64 + (s8 ^ ((c_my&7)<<3))) = make_uint2(p0, p1);
    }
    __syncthreads();
    #pragma unroll
    for (int kk = 0; kk < 2; kk++){
      int kb = kk*32 + g4*8;
      long af[8];
      #pragma unroll
      for (int ci = 0; ci < 8; ci++){
        int row = wm*128 + ci*16 + lr;
        af[ci] = *(const long*)(Ut + row*64 + (kb ^ ((row&7)<<3)));
      }
      #pragma unroll
      for (int cj = 0; cj < 4; cj++){
        int row = wn*64 + cj*16 + lr;
        long bfr = *(const long*)(Ut + row*64 + (kb ^ ((row&7)<<3)));
        #pragma unroll
        for (int ci = 0; ci < 8; ci++)
          acc[ci][cj] = __builtin_amdgcn_mfma_f32_16x16x32_fp8_fp8(af[ci], bfr, acc[ci][cj], 0,0,0);
      }
    }
  }
  const float sc = 1.0f/256.0f;   // undo (16)^2 scale
  ushortt* dst = Mpart + (size_t)blk*65536;
  #pragma unroll
  for (int ci = 0; ci < 8; ci++){
    #pragma unroll
    for (int cj = 0; cj < 4; cj++){
      int c2 = wn*64 + cj*16 + lr;
      #pragma unroll
      for (int r = 0; r < 4; r++){
        int c1 = wm*128 + ci*16 + g4*4 + r;
        dst[(size_t)c1*256 + c2] = f2bf(acc[ci][cj][r]*sc);
      }
    }
  }
}

__global__ __launch_bounds__(256) void mreduce_kernel(const ushortt* __restrict__ Mpart,
                                                      float* __restrict__ Mm)
{
  int i = blockIdx.x*256 + threadIdx.x;
  float s = 0.f;
  for (int p = 0; p < 256; p++) s += bf2f(Mpart[(size_t)p*65536 + i]);
  Mm[i] = s;
}

// ---------------- fold attn BN into w1f8 (fp8 x64) + b1eff2 (x4) ----------------
__global__ __launch_bounds__(256) void bn2_final(
    const float* __restrict__ Mm, const float* __restrict__ mu_sum,
    const float* __restrict__ aw1,
    const float* __restrict__ ag, const float* __restrict__ abeta,
    u8* __restrict__ w1f8, float* __restrict__ b1eff2)
{
  __shared__ float wrow[256];
  __shared__ float red[8];
  __shared__ float s2s;
  int t = threadIdx.x;
  int ch = blockIdx.x;
  wrow[t] = aw1[(size_t)ch*256 + t];
  __syncthreads();
  float colacc = 0.f;
  for (int r = 0; r < 256; r++) colacc += wrow[r] * Mm[(size_t)r*256 + t];
  float inv = 1.0f/(float)NSAMP;
  float qpart = colacc * wrow[t] * inv;
  float dpart = wrow[t] * mu_sum[t] * inv;
  for (int off=32; off; off>>=1){ qpart += __shfl_xor(qpart, off); dpart += __shfl_xor(dpart, off); }
  if ((t&63)==0){ red[t>>6] = qpart; red[4 + (t>>6)] = dpart; }
  __syncthreads();
  if (t == 0){
    float quad = red[0]+red[1]+red[2]+red[3];
    float dot  = red[4]+red[5]+red[6]+red[7];
    float var = quad - dot*dot;
    float s2 = ag[ch] * rsqrtf(var + 1e-5f);
    b1eff2[ch] = 4.f*(abeta[ch] - dot*s2);   // pre-scaled x4: H = fp8(4*relu(.))
    s2s = s2;
  }
  __syncthreads();
  w1f8[(size_t)ch*256 + t] = f2fp8(64.f*wrow[t]*s2s);
}

// ---------------- GEMM1 (fp8, 128B-pitch LDS, XCD swizzle): H = fp8(relu(.)*4) ----------------
// acc = (16u)*(64w1) = 1024*(u.w1); v4 = acc/256 + b1eff2(x4); H = fp8u(v4)
__global__ __launch_bounds__(512) void gemm1_kernel(
    const u8* __restrict__ U8c, const u8* __restrict__ w1f8,
    const float* __restrict__ b1eff2, u8* __restrict__ H)
{
  __shared__ u8 As8[128*128];   // 16 KB
  __shared__ u8 Bs8[256*128];   // 32 KB (reused as repack)
  int t = threadIdx.x;
  int w = t >> 6, l = t & 63;
  int lr = l & 15, g4 = l >> 4;
  int wm = w >> 2, wn = w & 3;
  int nwg = gridDim.x, cpx = nwg >> 3;
  int logical = (blockIdx.x & 7)*cpx + (blockIdx.x >> 3);
  int mt = logical >> 2, nt = logical & 3;
  int s0 = mt*128, n0 = nt*256;

  f32x4 acc[4][4];
  #pragma unroll
  for (int i=0;i<4;i++) for (int j=0;j<4;j++) acc[i][j] = (f32x4){0.f,0.f,0.f,0.f};

  for (int kt = 0; kt < 2; kt++){
    int k0 = kt*128;
    __syncthreads();
    #pragma unroll
    for (int i = 0; i < 2; i++){
      int c = t + i*512;
      int r = c >> 3, db = (c & 7)*16;
      const u8* src = U8c + (size_t)(s0+r)*256 + k0 + (db ^ ((r&7)<<4));
      gload16(src, As8 + c*16);
    }
    #pragma unroll
    for (int i = 0; i < 4; i++){
      int c = t + i*512;
      int r = c >> 3, db = (c & 7)*16;
      const u8* src = w1f8 + (size_t)(n0+r)*256 + k0 + (db ^ ((r&7)<<4));
      gload16(src, Bs8 + c*16);
    }
    __syncthreads();
    #pragma unroll
    for (int kk = 0; kk < 4; kk++){
      int kb = kk*32 + g4*8;
      long af[4];
      #pragma unroll
      for (int mi = 0; mi < 4; mi++){
        int row = wm*64 + mi*16 + lr;
        af[mi] = *(const long*)(As8 + row*128 + (kb ^ ((row&7)<<4)));
      }
      #pragma unroll
      for (int ni = 0; ni < 4; ni++){
        int row = wn*64 + ni*16 + lr;
        long bfr = *(const long*)(Bs8 + row*128 + (kb ^ ((row&7)<<4)));
        #pragma unroll
        for (int mi = 0; mi < 4; mi++)
          acc[mi][ni] = __builtin_amdgcn_mfma_f32_16x16x32_fp8_fp8(af[mi], bfr, acc[mi][ni], 0,0,0);
      }
    }
  }
  // epilogue: scale 1/256, bias(x4), relu -> fp8 -> LINEAR LDS repack -> coalesced stores
  const float sc1 = 1.0f/256.0f;
  __syncthreads();
  u8* rep = Bs8;                   // 128 x 256 fp8 = 32 KB
  #pragma unroll
  for (int ni = 0; ni < 4; ni++){
    int colc = wn*64 + ni*16 + lr;
    float bias = b1eff2[n0 + colc];
    #pragma unroll
    for (int mi = 0; mi < 4; mi++){
      int sloc = wm*64 + mi*16 + g4*4;
      #pragma unroll
      for (int r = 0; r < 4; r++){
        float v = acc[mi][ni][r]*sc1 + bias;
        v = v > 0.f ? v : 0.f;
        rep[(sloc+r)*256 + colc] = f2fp8u(v);
      }
    }
  }
  __syncthreads();
  #pragma unroll
  for (int i = 0; i < 4; i++){
    int e = t + i*512;
    int row = e >> 4, off = (e & 15)*16;
    *(uint4*)&H[(size_t)(s0+row)*1024 + n0 + off] = *(const uint4*)(rep + e*16);
  }
}

// ---------------- GEMM2 (fp8, 128B-pitch LDS, XCD swizzle): logits + softmax + agg ----------------
__global__ __launch_bounds__(512) void gemm2_kernel(
    const u8* __restrict__ H, const u8* __restrict__ w2f8,
    const float* __restrict__ ab2, const u8* __restrict__ val8,
    float* __restrict__ aggT, int s_off)
{
  __shared__ u8 As8[128*128];   // 16 KB
  __shared__ u8 Bs8[256*128];   // 32 KB
  int t = threadIdx.x;
  int w = t >> 6, l = t & 63;
  int lr = l & 15, g4 = l >> 4;
  int wm = w >> 2, wn = w & 3;
  int nwg = gridDim.x, cpx = nwg >> 3;
  int blk = (blockIdx.x & 7)*cpx + (blockIdx.x >> 3);   // match gemm1's H->XCD mapping
  int s0 = blk*128;

  f32x4 acc[4][4];
  #pragma unroll
  for (int i=0;i<4;i++) for (int j=0;j<4;j++) acc[i][j] = (f32x4){0.f,0.f,0.f,0.f};

  for (int kt = 0; kt < 8; kt++){
    int k0 = kt*128;
    __syncthreads();
    #pragma unroll
    for (int i = 0; i < 2; i++){
      int c = t + i*512;
      int r = c >> 3, db = (c & 7)*16;
      const u8* src = H + (size_t)(s0+r)*1024 + k0 + (db ^ ((r&7)<<4));
      gload16(src, As8 + c*16);
    }
    #pragma unroll
    for (int i = 0; i < 4; i++){
      int c = t + i*512;
      int r = c >> 3, db = (c & 7)*16;
      const u8* src = w2f8 + (size_t)r*1024 + k0 + (db ^ ((r&7)<<4));
      gload16(src, Bs8 + c*16);
    }
    __syncthreads();
    #pragma unroll
    for (int kk = 0; kk < 4; kk++){
      int kb = kk*32 + g4*8;
      long af[4];
      #pragma unroll
      for (int mi = 0; mi < 4; mi++){
        int row = wm*64 + mi*16 + lr;
        af[mi] = *(const long*)(As8 + row*128 + (kb ^ ((row&7)<<4)));
      }
      #pragma unroll
      for (int ni = 0; ni < 4; ni++){
        int row = wn*64 + ni*16 + lr;
        long bfr = *(const long*)(Bs8 + row*128 + (kb ^ ((row&7)<<4)));
        #pragma unroll
        for (int mi = 0; mi < 4; mi++)
          acc[mi][ni] = __builtin_amdgcn_mfma_f32_16x16x32_fp8_fp8(af[mi], bfr, acc[mi][ni], 0,0,0);
      }
    }
  }
  const float sc = 1.0f/1024.0f;   // undo W2*256 and H*4
  int ptbase = s_off >> 4;
  #pragma unroll
  for (int mi = 0; mi < 4; mi++){
    int pt = ptbase + blk*8 + wm*4 + mi;
    int sbase = pt*16;
    #pragma unroll
    for (int ni = 0; ni < 4; ni++){
      int d = wn*64 + ni*16 + lr;
      float bias = ab2[d];
      float lg[4];
      #pragma unroll
      for (int r = 0; r < 4; r++) lg[r] = acc[mi][ni][r]*sc + bias;
      float mx = fmaxf(fmaxf(lg[0],lg[1]), fmaxf(lg[2],lg[3]));
      mx = fmaxf(mx, __shfl_xor(mx, 16));
      mx = fmaxf(mx, __shfl_xor(mx, 32));
      float ev[4], ss = 0.f;
      #pragma unroll
      for (int r = 0; r < 4; r++){ ev[r] = __expf(lg[r]-mx); ss += ev[r]; }
      ss += __shfl_xor(ss, 16);
      ss += __shfl_xor(ss, 32);
      float inv = 1.0f/(ss*16.f);   // includes val8 1/16 descale
      float pa = 0.f;
      #pragma unroll
      for (int r = 0; r < 4; r++){
        int s = sbase + g4*4 + r;
        pa += ev[r]*inv*fp82f(val8[(size_t)s*256 + d]);
      }
      pa += __shfl_xor(pa, 16);
      pa += __shfl_xor(pa, 32);
      if (g4 == 0) aggT[(size_t)pt*256 + d] = pa;
    }
  }
}

// ---------------- final: out = end_w @ agg + end_b + valueT ----------------
__global__ __launch_bounds__(256) void final_kernel(
    const float* __restrict__ aggT, const float* __restrict__ endwT,
    const float* __restrict__ endb, const float* __restrict__ valueT,
    float* __restrict__ out)
{
  __shared__ float ags[32*257];
  int t = threadIdx.x;
  int tile = blockIdx.x & 63, b = blockIdx.x >> 6;
  int n0 = tile*32;
  for (int e = t; e < 32*256; e += 256){
    int nn = e >> 8, d = e & 255;
    ags[nn*257 + d] = aggT[(size_t)(b*Nv + n0 + nn)*256 + d];
  }
  __syncthreads();
  int cg = t >> 2, ng = t & 3;
  int co0 = cg*2, nb = ng*8;
  float acc[2][8];
  for (int i=0;i<2;i++){ float bb = endb[co0+i]; for (int j=0;j<8;j++) acc[i][j]=bb; }
  for (int d = 0; d < 256; d++){
    float w0 = endwT[d*128 + co0], w1 = endwT[d*128 + co0 + 1];
    #pragma unroll
    for (int j=0;j<8;j++){
      float av = ags[(nb+j)*257 + d];
      acc[0][j] += w0*av; acc[1][j] += w1*av;
    }
  }
  for (int i=0;i<2;i++){
    for (int j=0;j<8;j++){
      int n = n0 + nb + j;
      size_t o = (size_t)(b*128 + co0 + i)*Nv + n;
      out[o] = acc[i][j] + valueT[(size_t)(b*Nv + n)*128 + co0 + i];
    }
  }
}

extern "C" void kernel_launch(void* const* d_in, const int* in_sizes, int n_in,
                              void* d_out, int out_size, void* d_ws, size_t ws_size,
                              hipStream_t stream)
{
  (void)in_sizes; (void)n_in; (void)out_size;
  const float* pos   = (const float*)d_in[0];
  const float* key   = (const float*)d_in[1];
  const float* query = (const float*)d_in[2];
  const float* mw1   = (const float*)d_in[3];
  const float* mb1   = (const float*)d_in[4];
  const float* mw2   = (const float*)d_in[5];
  const float* mb2   = (const float*)d_in[6];
  const float* mwsc  = (const float*)d_in[7];
  const float* mbsc  = (const float*)d_in[8];
  const float* wk    = (const float*)d_in[9];
  const float* bk    = (const float*)d_in[10];
  const float* wq    = (const float*)d_in[11];
  const float* bq    = (const float*)d_in[12];
  const float* wv    = (const float*)d_in[13];
  const float* bv    = (const float*)d_in[14];
  const float* pw1   = (const float*)d_in[15];
  const float* pg    = (const float*)d_in[17];
  const float* pbeta = (const float*)d_in[18];
  const float* pw2   = (const float*)d_in[19];
  const float* pb2   = (const float*)d_in[20];
  const float* aw1   = (const float*)d_in[21];
  const float* ag    = (const float*)d_in[23];
  const float* abeta = (const float*)d_in[24];
  const float* aw2   = (const float*)d_in[25];
  const float* ab2   = (const float*)d_in[26];
  const float* endw  = (const float*)d_in[27];
  const float* endb  = (const float*)d_in[28];
  float* out = (float*)d_out;

  char* wsb = (char*)d_ws;
  size_t off = 0;
  auto take = [&](size_t bytes)->char*{
    char* p = wsb + off; off += (bytes + 255) & ~(size_t)255; return p;
  };
  float* Mm      = (float*)take(65536*4);
  float* mu_sum  = (float*)take(256*4);     // zeroed
  float* rstat   = (float*)take(12*4);      // zeroed
  size_t zero_bytes = off;
  float* b1eff2  = (float*)take(1024*4);
  float* valueT  = (float*)take((size_t)524288*4);     // [4096 x 128] f32
  float* aggT    = (float*)take((size_t)1048576*4);
  float* endwT   = (float*)take(32768*4);
  int*   idxb    = (int*)take(65536*4);
  ushortt* qT    = (ushortt*)take((size_t)1048576*2);  // bf16 [4096 x 256]
  ushortt* kT    = (ushortt*)take((size_t)1048576*2);
  ushortt* vT    = (ushortt*)take((size_t)1048576*2);
  ushortt* hx16  = (ushortt*)take((size_t)4096*384*2); // [4096 x 384] bf16 (h | x)
  ushortt* wA16  = (ushortt*)take((size_t)768*256*2);
  ushortt* wB16  = (ushortt*)take((size_t)128*384*2);
  ushortt* wv16  = (ushortt*)take((size_t)256*128*2);
  u8*      U8b   = (u8*)take((size_t)16777216);        // fp8 u (x16): gemm1 + mm
  u8*      val8  = (u8*)take((size_t)16777216);        // fp8 (v + pos_emb) (x16)
  ushortt* hposR = (ushortt*)take((size_t)4194304*2);  // bf16 Hpos [65536x64]
  ushortt* Mpart = (ushortt*)take((size_t)256*65536*2);// bf16 M partials (32 MB)
  u8*      w1f8  = (u8*)take((size_t)262144);          // fp8 W1eff (x64)
  u8*      w2f8  = (u8*)take((size_t)262144);          // fp8 W2 (x256)
  ushortt* pw2R  = (ushortt*)take(16384*2);

  // H (fp8) gets whatever is left; chunk the sample dim to fit.
  size_t avail = (ws_size > off) ? (ws_size - off) : 0;
  int nch = 1;
  while (nch < 64 && ((size_t)(NSAMP/nch))*1024 > avail) nch <<= 1;
  int chunk = NSAMP / nch;          // >= 1024, multiple of 128
  u8* H = (u8*)(wsb + off);

  hipMemsetAsync(d_ws, 0, zero_bytes, stream);
  prep_kernel<<<640,256,0,stream>>>(wk,wq,wv,endw,mw1,mw2,mwsc,aw2,pw2,key,query,
                                    wA16,wB16,wv16,endwT,w2f8,pw2R,hx16);
  knn_kernel<<<1024,256,0,stream>>>(pos,idxb);
  gemmA_kernel<<<dim3(32,3),512,0,stream>>>(hx16,wA16,mb1,bk,bq,kT,qT);
  gemmBC_kernel<<<32,512,0,stream>>>(hx16,wB16,mb2,mbsc,wv16,bv,valueT,vT);
  bn1_stats<<<64,256,0,stream>>>(pos,idxb,rstat);
  hpos_kernel<<<2048,256,0,stream>>>(pos,idxb,rstat,pw1,pg,pbeta,hposR);
  gemm0_kernel<<<512,512,0,stream>>>(hposR,pw2R,pb2,idxb,qT,kT,vT,U8b,val8,mu_sum);
  mm_kernel<<<256,512,0,stream>>>(U8b,Mpart);
  mreduce_kernel<<<256,256,0,stream>>>(Mpart,Mm);
  bn2_final<<<1024,256,0,stream>>>(Mm,mu_sum,aw1,ag,abeta,w1f8,b1eff2);
  for (int cc = 0; cc < nch; cc++){
    int s_off = cc*chunk;
    gemm1_kernel<<<(chunk/128)*4,512,0,stream>>>(U8b + (size_t)s_off*256, w1f8, b1eff2, H);
    gemm2_kernel<<<chunk/128,512,0,stream>>>(H, w2f8, ab2, val8, aggT, s_off);
  }
  final_kernel<<<128,256,0,stream>>>(aggT,endwT,endb,valueT,out);
}

// Round 23
// 271.182 us; speedup vs baseline: 1.0616x; 1.0616x over previous
//
#include <hip/hip_runtime.h>
#include <hip/hip_bf16.h>
#include <math.h>

#define Bv 2
#define Nv 2048
#define Cv 128
#define Dv 256
#define PHv 64
#define AHv 1024
#define Kv 16
#define NSAMP (Bv*Nv*Kv)   // 65536

typedef unsigned short ushortt;
typedef unsigned char u8;
typedef __attribute__((ext_vector_type(8))) short bf16x8;
typedef __attribute__((ext_vector_type(4))) float f32x4;

__device__ __forceinline__ float bf2f(ushortt h){
  union { unsigned int u; float f; } v; v.u = ((unsigned int)h) << 16; return v.f;
}
__device__ __forceinline__ ushortt f2bf(float f){
  union { unsigned int u; float f; } v; v.f = f;
  unsigned int r = v.u + 0x7FFFu + ((v.u >> 16) & 1u);
  return (ushortt)(r >> 16);
}
// f32 -> fp8 e4m3fn (OCP), RNE, clamp to 448, FTZ subnormals
__device__ __forceinline__ u8 f2fp8(float f){
  union { float f; unsigned int u; } v; v.f = f;
  unsigned int s = (v.u >> 24) & 0x80u;
  unsigned int a = v.u & 0x7FFFFFFFu;
  if (a > 0x43E00000u) a = 0x43E00000u;           // 448.0
  unsigned int r = a + 0x7FFFFu + ((a >> 20) & 1u);
  int e = (int)((r >> 23) & 0xFF) - 120;          // -127 + 7
  unsigned int m = (r >> 20) & 7u;
  if (e <= 0) return (u8)s;
  return (u8)(s | ((unsigned)e << 3) | m);
}
// non-negative fast path (post-relu): same result as f2fp8 for f >= 0
__device__ __forceinline__ u8 f2fp8u(float f){
  union { float f; unsigned int u; } v; v.f = f;
  unsigned int a = v.u;
  if (a > 0x43E00000u) a = 0x43E00000u;
  unsigned int r = a + 0x7FFFFu + ((a >> 20) & 1u);
  unsigned int out = (r >> 20) - 960u;            // ((e)<<3)|m
  return (u8)(r < 0x3C800000u ? 0u : out);
}

__device__ __forceinline__ void gload16(const void* g, void* l){
  __builtin_amdgcn_global_load_lds(
      (const __attribute__((address_space(1))) unsigned int*)g,
      (__attribute__((address_space(3))) unsigned int*)l, 16, 0, 0);
}

// ---------------- prep: weight packs / casts + xcat (grid-split) ----------------
__global__ __launch_bounds__(256) void prep_kernel(
    const float* __restrict__ wk, const float* __restrict__ wq,
    const float* __restrict__ wv, const float* __restrict__ endw,
    const float* __restrict__ mw1, const float* __restrict__ mw2,
    const float* __restrict__ mwsc, const float* __restrict__ aw2,
    const float* __restrict__ pw2,
    const float* __restrict__ key, const float* __restrict__ query,
    ushortt* __restrict__ wA16, ushortt* __restrict__ wB16, ushortt* __restrict__ wv16,
    float* __restrict__ endwT, u8* __restrict__ w2f8, ushortt* __restrict__ pw2R,
    ushortt* __restrict__ hx16)
{
  __shared__ float xs[256*33];
  int t = threadIdx.x;
  if (blockIdx.x < 128){
    int tile = blockIdx.x & 63, b = blockIdx.x >> 6;
    int n0 = tile*32;
    for (int e = t; e < 256*32; e += 256){
      int c = e >> 5, nn = e & 31;
      xs[c*33+nn] = (c < 128) ? key[(size_t)(b*128+c)*Nv + n0+nn]
                              : query[(size_t)(b*128+(c-128))*Nv + n0+nn];
    }
    __syncthreads();
    int nn = t & 31, cg = t >> 5;    // cg 0..7
    size_t s = (size_t)b*Nv + n0 + nn;
    __align__(16) ushortt tmp[32];
    #pragma unroll
    for (int cc = 0; cc < 32; cc++) tmp[cc] = f2bf(xs[(cg*32+cc)*33 + nn]);
    uint4* dst = (uint4*)&hx16[s*384 + 128 + cg*32];
    #pragma unroll
    for (int q = 0; q < 4; q++) dst[q] = ((uint4*)tmp)[q];
    return;
  }
  int tid = (blockIdx.x-128)*256 + t;
  int stride = (gridDim.x-128)*256;
  for (int i = tid; i < 768*256; i += stride){
    int r = i >> 8, c = i & 255;
    float v;
    if (r < 128) v = mw1[r*256 + c];
    else if (r < 384) v = (c < 128) ? wk[(r-128)*128 + c] : 0.f;
    else if (r < 640) v = (c >= 128) ? wq[(r-384)*128 + (c-128)] : 0.f;
    else v = 0.f;
    wA16[i] = f2bf(v);
  }
  for (int i = tid; i < 128*384; i += stride){
    int r = i / 384, c = i - r*384;
    float v = (c < 128) ? mw2[r*128 + c] : mwsc[r*256 + (c-128)];
    wB16[i] = f2bf(v);
  }
  for (int i = tid; i < 256*128; i += stride) wv16[i] = f2bf(wv[i]);
  for (int i = tid; i < 128*256; i += stride){ int co = i>>8, d = i&255; endwT[d*128+co] = endw[i]; }
  for (int i = tid; i < 256*1024; i += stride) w2f8[i] = f2fp8(aw2[i]*256.f);
  for (int i = tid; i < 256*64; i += stride) pw2R[i] = f2bf(pw2[i]);
}

// ---------------- gemmA: [4096 x 768 x K=256] -> h(relu,bf16), kT16, qT16 ----------------
__global__ __launch_bounds__(512) void gemmA_kernel(
    ushortt* __restrict__ hx16, const ushortt* __restrict__ wA16,
    const float* __restrict__ mb1, const float* __restrict__ bk, const float* __restrict__ bq,
    ushortt* __restrict__ kT, ushortt* __restrict__ qT)
{
  __shared__ ushortt As[128*64];
  __shared__ ushortt Bs[256*64];
  int t = threadIdx.x;
  int w = t >> 6, l = t & 63;
  int lr = l & 15, g4 = l >> 4;
  int wm = w >> 2, wn = w & 3;
  int s0 = blockIdx.x*128, n0 = blockIdx.y*256;

  f32x4 acc[4][4];
  #pragma unroll
  for (int i=0;i<4;i++) for (int j=0;j<4;j++) acc[i][j] = (f32x4){0.f,0.f,0.f,0.f};

  for (int kt = 0; kt < 4; kt++){
    int k0 = kt*64;
    __syncthreads();
    #pragma unroll
    for (int i = 0; i < 2; i++){
      int c = t + i*512;
      int r = c >> 3, db = (c & 7)*16;
      const ushortt* src = hx16 + (size_t)(s0+r)*384 + 128 + k0 + ((db ^ ((r&7)<<4))>>1);
      gload16(src, As + c*8);
    }
    #pragma unroll
    for (int i = 0; i < 4; i++){
      int c = t + i*512;
      int r = c >> 3, db = (c & 7)*16;
      const ushortt* src = wA16 + (size_t)(n0+r)*256 + k0 + ((db ^ ((r&7)<<4))>>1);
      gload16(src, Bs + c*8);
    }
    __syncthreads();
    #pragma unroll
    for (int kk = 0; kk < 2; kk++){
      int kb = kk*64 + g4*16;
      bf16x8 af[4];
      #pragma unroll
      for (int mi = 0; mi < 4; mi++){
        int row = wm*64 + mi*16 + lr;
        af[mi] = *(const bf16x8*)((const char*)As + row*128 + (kb ^ ((row&7)<<4)));
      }
      #pragma unroll
      for (int ni = 0; ni < 4; ni++){
        int row = wn*64 + ni*16 + lr;
        bf16x8 bfr = *(const bf16x8*)((const char*)Bs + row*128 + (kb ^ ((row&7)<<4)));
        #pragma unroll
        for (int mi = 0; mi < 4; mi++)
          acc[mi][ni] = __builtin_amdgcn_mfma_f32_16x16x32_bf16(af[mi], bfr, acc[mi][ni], 0,0,0);
      }
    }
  }
  #pragma unroll
  for (int ni = 0; ni < 4; ni++){
    int col = n0 + wn*64 + ni*16 + lr;
    if (col < 128){
      float bias = mb1[col];
      #pragma unroll
      for (int mi = 0; mi < 4; mi++){
        int rbase = s0 + wm*64 + mi*16 + g4*4;
        #pragma unroll
        for (int r = 0; r < 4; r++){
          float v = acc[mi][ni][r] + bias;
          v = v > 0.f ? v : 0.f;
          hx16[(size_t)(rbase+r)*384 + col] = f2bf(v);
        }
      }
    } else if (col < 384){
      float bias = bk[col-128];
      #pragma unroll
      for (int mi = 0; mi < 4; mi++){
        int rbase = s0 + wm*64 + mi*16 + g4*4;
        #pragma unroll
        for (int r = 0; r < 4; r++)
          kT[(size_t)(rbase+r)*256 + (col-128)] = f2bf(acc[mi][ni][r] + bias);
      }
    } else if (col < 640){
      float bias = bq[col-384];
      #pragma unroll
      for (int mi = 0; mi < 4; mi++){
        int rbase = s0 + wm*64 + mi*16 + g4*4;
        #pragma unroll
        for (int r = 0; r < 4; r++)
          qT[(size_t)(rbase+r)*256 + (col-384)] = f2bf(acc[mi][ni][r] + bias);
      }
    }
  }
}

// ---------------- gemmBC: valueT = hx @ wB^T + b ; vT16 = value16 @ wv^T + bv (fused) ----------------
__global__ __launch_bounds__(512) void gemmBC_kernel(
    const ushortt* __restrict__ hx16, const ushortt* __restrict__ wB16,
    const float* __restrict__ mb2, const float* __restrict__ mbsc,
    const ushortt* __restrict__ wv16, const float* __restrict__ bv,
    float* __restrict__ valueT, ushortt* __restrict__ vT)
{
  __shared__ char arena[65536];
  ushortt* As = (ushortt*)arena;
  ushortt* Bs = (ushortt*)(arena + 16384);
  ushortt* Ws = (ushortt*)arena;
  char*    Vs = arena + 32768;
  int t = threadIdx.x;
  int w = t >> 6, l = t & 63;
  int lr = l & 15, g4 = l >> 4;
  int wm = w >> 2, wn = w & 3;
  int s0 = blockIdx.x*128;

  {
    f32x4 acc[4][2];
    #pragma unroll
    for (int i=0;i<4;i++) for (int j=0;j<2;j++) acc[i][j] = (f32x4){0.f,0.f,0.f,0.f};

    for (int kt = 0; kt < 6; kt++){
      int k0 = kt*64;
      __syncthreads();
      #pragma unroll
      for (int i = 0; i < 2; i++){
        int c = t + i*512;
        int r = c >> 3, db = (c & 7)*16;
        const ushortt* src = hx16 + (size_t)(s0+r)*384 + k0 + ((db ^ ((r&7)<<4))>>1);
        gload16(src, As + c*8);
      }
      #pragma unroll
      for (int i = 0; i < 2; i++){
        int c = t + i*512;
        int r = c >> 3, db = (c & 7)*16;
        const ushortt* src = wB16 + (size_t)r*384 + k0 + ((db ^ ((r&7)<<4))>>1);
        gload16(src, Bs + c*8);
      }
      __syncthreads();
      #pragma unroll
      for (int kk = 0; kk < 2; kk++){
        int kb = kk*64 + g4*16;
        bf16x8 af[4];
        #pragma unroll
        for (int mi = 0; mi < 4; mi++){
          int row = wm*64 + mi*16 + lr;
          af[mi] = *(const bf16x8*)((const char*)As + row*128 + (kb ^ ((row&7)<<4)));
        }
        #pragma unroll
        for (int ni = 0; ni < 2; ni++){
          int row = wn*32 + ni*16 + lr;
          bf16x8 bfr = *(const bf16x8*)((const char*)Bs + row*128 + (kb ^ ((row&7)<<4)));
          #pragma unroll
          for (int mi = 0; mi < 4; mi++)
            acc[mi][ni] = __builtin_amdgcn_mfma_f32_16x16x32_bf16(af[mi], bfr, acc[mi][ni], 0,0,0);
        }
      }
    }
    #pragma unroll
    for (int ni = 0; ni < 2; ni++){
      int col = wn*32 + ni*16 + lr;
      float bias = mb2[col] + mbsc[col];
      #pragma unroll
      for (int mi = 0; mi < 4; mi++){
        int rloc = wm*64 + mi*16 + g4*4;
        #pragma unroll
        for (int r = 0; r < 4; r++){
          float v = acc[mi][ni][r] + bias;
          valueT[(size_t)(s0+rloc+r)*128 + col] = v;
          int row = rloc + r;
          *(ushortt*)(Vs + row*256 + ((col*2) ^ ((row&7)<<4))) = f2bf(v);
        }
      }
    }
  }
  {
    f32x4 acc2[4][4];
    #pragma unroll
    for (int i=0;i<4;i++) for (int j=0;j<4;j++) acc2[i][j] = (f32x4){0.f,0.f,0.f,0.f};

    for (int kt = 0; kt < 2; kt++){
      int k0 = kt*64;
      __syncthreads();
      #pragma unroll
      for (int i = 0; i < 4; i++){
        int c = t + i*512;
        int r = c >> 3, db = (c & 7)*16;
        const ushortt* src = wv16 + (size_t)r*128 + k0 + ((db ^ ((r&7)<<4))>>1);
        gload16(src, Ws + c*8);
      }
      __syncthreads();
      #pragma unroll
      for (int kk = 0; kk < 2; kk++){
        int kb = kk*64 + g4*16;
        bf16x8 af[4];
        #pragma unroll
        for (int mi = 0; mi < 4; mi++){
          int row = wm*64 + mi*16 + lr;
          af[mi] = *(const bf16x8*)(Vs + row*256 + ((kt*128 + kb) ^ ((row&7)<<4)));
        }
        #pragma unroll
        for (int ni = 0; ni < 4; ni++){
          int row = wn*64 + ni*16 + lr;
          bf16x8 bfr = *(const bf16x8*)((const char*)Ws + row*128 + (kb ^ ((row&7)<<4)));
          #pragma unroll
          for (int mi = 0; mi < 4; mi++)
            acc2[mi][ni] = __builtin_amdgcn_mfma_f32_16x16x32_bf16(af[mi], bfr, acc2[mi][ni], 0,0,0);
        }
      }
    }
    #pragma unroll
    for (int ni = 0; ni < 4; ni++){
      int col = wn*64 + ni*16 + lr;
      float bias = bv[col];
      #pragma unroll
      for (int mi = 0; mi < 4; mi++){
        int rbase = s0 + wm*64 + mi*16 + g4*4;
        #pragma unroll
        for (int r = 0; r < 4; r++)
          vT[(size_t)(rbase+r)*256 + col] = f2bf(acc2[mi][ni][r] + bias);
      }
    }
  }
}

// ---------------- KNN: wave-per-point, pure shfl ----------------
__global__ __launch_bounds__(256) void knn_kernel(const float* __restrict__ pos, int* __restrict__ idx)
{
  int t = threadIdx.x;
  int w = t >> 6, l = t & 63;
  int p = blockIdx.x*4 + w;
  int i = p & (Nv-1), b = p >> 11;
  const float* px = pos + (size_t)b*3*Nv;
  float pix = px[i], piy = px[Nv+i], piz = px[2*Nv+i];
  float sqi = pix*pix + piy*piy + piz*piz;
  float ds[32];
  #pragma unroll
  for (int jj = 0; jj < 32; jj++){
    int j = jj*64 + l;
    float qx = px[j], qy = px[Nv+j], qz = px[2*Nv+j];
    float sqj = qx*qx + qy*qy + qz*qz;
    float dot = pix*qx + piy*qy + piz*qz;
    ds[jj] = (sqi + sqj) - 2.0f*dot;
  }
  #pragma unroll 1
  for (int it = 0; it < 16; it++){
    float bv = 3.4e38f; int bj = 0x7FFFFFFF;
    #pragma unroll
    for (int jj = 0; jj < 32; jj++){
      int j = jj*64 + l;
      bool c = ds[jj] < bv;
      bv = c ? ds[jj] : bv;
      bj = c ? j : bj;
    }
    #pragma unroll
    for (int off = 32; off; off >>= 1){
      float ov = __shfl_xor(bv, off);
      int oj = __shfl_xor(bj, off);
      if (ov < bv || (ov == bv && oj < bj)){ bv = ov; bj = oj; }
    }
    if (l == 0) idx[(size_t)p*16 + it] = bj;
    #pragma unroll
    for (int jj = 0; jj < 32; jj++){
      if (jj*64 + l == bj) ds[jj] = 3.4e38f;
    }
  }
}

// ---------------- pos-BN stats ----------------
__global__ __launch_bounds__(256) void bn1_stats(const float* __restrict__ pos,
    const int* __restrict__ idx, float* __restrict__ rstat)
{
  int tid = blockIdx.x*256 + threadIdx.x;
  int stride = gridDim.x*256;
  float s[9] = {0,0,0,0,0,0,0,0,0};
  for (int e = tid; e < NSAMP; e += stride){
    int b = e >> 15;
    int rem = e & 32767;
    int n = rem >> 4, k = rem & 15;
    int j = idx[(size_t)(b*Nv+n)*16 + k];
    const float* px = pos + (size_t)b*3*Nv;
    float rx = px[n]-px[j], ry = px[Nv+n]-px[Nv+j], rz = px[2*Nv+n]-px[2*Nv+j];
    s[0]+=rx; s[1]+=ry; s[2]+=rz;
    s[3]+=rx*rx; s[4]+=rx*ry; s[5]+=rx*rz; s[6]+=ry*ry; s[7]+=ry*rz; s[8]+=rz*rz;
  }
  for (int off=32; off; off>>=1)
    for (int q=0;q<9;q++) s[q] += __shfl_xor(s[q], off);
  if ((threadIdx.x & 63) == 0)
    for (int q=0;q<9;q++) atomicAdd(&rstat[q], s[q]);
}

// ---------------- Hpos = relu(BN(W1 r)) -> bf16 [65536 x 64]; BN fold inlined ----------------
__global__ __launch_bounds__(256) void hpos_kernel(
    const float* __restrict__ pos, const int* __restrict__ idx,
    const float* __restrict__ rstat, const float* __restrict__ pw1,
    const float* __restrict__ pg, const float* __restrict__ pbeta,
    ushortt* __restrict__ hposR)
{
  __shared__ float w1s[192];
  __shared__ float b1s[64];
  int t = threadIdx.x;
  if (t < 64){
    float inv = 1.0f/(float)NSAMP;
    float mux = rstat[0]*inv, muy = rstat[1]*inv, muz = rstat[2]*inv;
    float xx = rstat[3]*inv, xy = rstat[4]*inv, xz = rstat[5]*inv;
    float yy = rstat[6]*inv, yz = rstat[7]*inv, zz = rstat[8]*inv;
    float w0 = pw1[t*3], w1 = pw1[t*3+1], w2 = pw1[t*3+2];
    float dot = w0*mux + w1*muy + w2*muz;
    float quad = w0*w0*xx + w1*w1*yy + w2*w2*zz + 2.f*(w0*w1*xy + w0*w2*xz + w1*w2*yz);
    float var = quad - dot*dot;
    float sc = pg[t] * rsqrtf(var + 1e-5f);
    w1s[t*3]   = w0*sc;
    w1s[t*3+1] = w1*sc;
    w1s[t*3+2] = w2*sc;
    b1s[t] = pbeta[t] - dot*sc;
  }
  __syncthreads();
  int s = blockIdx.x*32 + (t>>3);
  int c0 = (t&7)*8;
  int ptv = s >> 4;
  int n = ptv & (Nv-1), b = ptv >> 11;
  int j = idx[s];
  const float* px = pos + (size_t)b*3*Nv;
  float rx = px[n]-px[j], ry = px[Nv+n]-px[Nv+j], rz = px[2*Nv+n]-px[2*Nv+j];
  ushortt outv[8];
  #pragma unroll
  for (int e = 0; e < 8; e++){
    int c = c0+e;
    float v = b1s[c] + w1s[c*3]*rx + w1s[c*3+1]*ry + w1s[c*3+2]*rz;
    outv[e] = f2bf(v > 0.f ? v : 0.f);
  }
  *(uint4*)&hposR[(size_t)s*64 + c0] = *(uint4*)outv;
}

// ---------------- GEMM0: pe = Hpos @ pw2^T + pb2; epilogue: U8, val16, mu ----------------
__global__ __launch_bounds__(512) void gemm0_kernel(
    const ushortt* __restrict__ hposR, const ushortt* __restrict__ pw2R,
    const float* __restrict__ pb2, const int* __restrict__ idx,
    const ushortt* __restrict__ qT, const ushortt* __restrict__ kT, const ushortt* __restrict__ vT,
    u8* __restrict__ U8, ushortt* __restrict__ val16, float* __restrict__ mu_sum)
{
  __shared__ ushortt As[128*64];
  __shared__ ushortt Bs[256*64];   // reused as U8 repack after MFMA
  __shared__ float mured[8*256];
  int t = threadIdx.x;
  int w = t >> 6, l = t & 63;
  int lr = l & 15, g4 = l >> 4;
  int wm = w >> 2, wn = w & 3;
  int s0 = blockIdx.x*128;

  #pragma unroll
  for (int i = 0; i < 2; i++){
    int c = t + i*512;
    int r = c >> 3, db = (c & 7)*16;
    const ushortt* src = hposR + (size_t)(s0+r)*64 + ((db ^ ((r&7)<<4))>>1);
    gload16(src, As + c*8);
  }
  #pragma unroll
  for (int i = 0; i < 4; i++){
    int c = t + i*512;
    int r = c >> 3, db = (c & 7)*16;
    const ushortt* src = pw2R + (size_t)r*64 + ((db ^ ((r&7)<<4))>>1);
    gload16(src, Bs + c*8);
  }
  __syncthreads();

  f32x4 acc[4][4];
  #pragma unroll
  for (int i=0;i<4;i++) for (int j=0;j<4;j++) acc[i][j] = (f32x4){0.f,0.f,0.f,0.f};
  #pragma unroll
  for (int kk = 0; kk < 2; kk++){
    int kb = kk*64 + g4*16;
    bf16x8 af[4];
    #pragma unroll
    for (int mi = 0; mi < 4; mi++){
      int row = wm*64 + mi*16 + lr;
      af[mi] = *(const bf16x8*)((const char*)As + row*128 + (kb ^ ((row&7)<<4)));
    }
    #pragma unroll
    for (int ni = 0; ni < 4; ni++){
      int row = wn*64 + ni*16 + lr;
      bf16x8 bfr = *(const bf16x8*)((const char*)Bs + row*128 + (kb ^ ((row&7)<<4)));
      #pragma unroll
      for (int mi = 0; mi < 4; mi++)
        acc[mi][ni] = __builtin_amdgcn_mfma_f32_16x16x32_bf16(af[mi], bfr, acc[mi][ni], 0,0,0);
    }
  }
  __syncthreads();   // Bs dead; reuse as U8 repack arena
  u8* rep = (u8*)Bs; // 128 x 256 fp8 = 32 KB

  float musum[4] = {0.f,0.f,0.f,0.f};
  __align__(16) float pb2v[4];
  #pragma unroll
  for (int ni = 0; ni < 4; ni++) pb2v[ni] = pb2[wn*64 + ni*16 + lr];
  #pragma unroll
  for (int mi = 0; mi < 4; mi++){
    #pragma unroll
    for (int r4 = 0; r4 < 4; r4++){
      int sloc = wm*64 + mi*16 + g4*4 + r4;
      int s = s0 + sloc;
      int ptv = s >> 4;
      int b = s >> 15;
      int j = idx[s];
      const ushortt* krow = kT + (size_t)(b*Nv + j)*256;
      const ushortt* qrow = qT + (size_t)ptv*256;
      const ushortt* vrow = vT + (size_t)ptv*256;
      #pragma unroll
      for (int ni = 0; ni < 4; ni++){
        int d = wn*64 + ni*16 + lr;
        float pe = acc[mi][ni][r4] + pb2v[ni];
        float u = bf2f(qrow[d]) - bf2f(krow[d]) + pe;
        rep[sloc*256 + d] = f2fp8(16.f*u);
        val16[(size_t)s*256 + d] = f2bf(bf2f(vrow[d]) + pe);
        musum[ni] += u;
      }
    }
  }
  #pragma unroll
  for (int ni = 0; ni < 4; ni++)
    mured[(wm*4+g4)*256 + wn*64 + ni*16 + lr] = musum[ni];
  __syncthreads();
  // coalesced U8 store (linear)
  #pragma unroll
  for (int i = 0; i < 4; i++){
    int e = t + i*512;
    int row = e >> 4, off = (e & 15)*16;
    *(uint4*)&U8[(size_t)(s0+row)*256 + off] = *(const uint4*)(rep + e*16);
  }
  if (t < 256){
    float ssum = 0.f;
    #pragma unroll
    for (int q = 0; q < 8; q++) ssum += mured[q*256 + t];
    atomicAdd(&mu_sum[t], ssum);
  }
}

// ---------------- M partials (fp8: consumes U8 = fp8(16u); Mpart = acc/256) ----------------
__global__ __launch_bounds__(512) void mm_kernel(const u8* __restrict__ U8,
                                                 ushortt* __restrict__ Mpart)
{
  __shared__ u8 Ut[256*64];   // 16 KB fp8, [c][s], 64B pitch, XOR swizzle (row&7)<<3
  int t = threadIdx.x;
  int w = t >> 6, l = t & 63;
  int lr = l & 15, g4 = l >> 4;
  int wm = w >> 2, wn = w & 3;
  int c_my = ((w & 3)*64 + l);
  int sg = w >> 2;
  int blk = blockIdx.x;
  int sstart = blk*256;

  f32x4 acc[8][4];
  #pragma unroll
  for (int i=0;i<8;i++) for (int j=0;j<4;j++) acc[i][j] = (f32x4){0.f,0.f,0.f,0.f};

  for (int st = 0; st < 4; st++){
    int sb = sstart + st*64;
    __syncthreads();
    #pragma unroll
    for (int g = 0; g < 4; g++){
      int s8 = sg*32 + g*8;
      unsigned int p0 = 0, p1 = 0;
      #pragma unroll
      for (int e = 0; e < 4; e++)
        p0 |= (unsigned int)U8[(size_t)(sb + s8 + e)*256 + c_my] << (8*e);
      #pragma unroll
      for (int e = 0; e < 4; e++)
        p1 |= (unsigned int)U8[(size_t)(sb + s8 + 4 + e)*256 + c_my] << (8*e);
      *(uint2*)(Ut + c_my*64 + (s8 ^ ((c_my&7)<<3))) = make_uint2(p0, p1);
    }
    __syncthreads();
    #pragma unroll
    for (int kk = 0; kk < 2; kk++){
      int kb = kk*32 + g4*8;
      long af[8];
      #pragma unroll
      for (int ci = 0; ci < 8; ci++){
        int row = wm*128 + ci*16 + lr;
        af[ci] = *(const long*)(Ut + row*64 + (kb ^ ((row&7)<<3)));
      }
      #pragma unroll
      for (int cj = 0; cj < 4; cj++){
        int row = wn*64 + cj*16 + lr;
        long bfr = *(const long*)(Ut + row*64 + (kb ^ ((row&7)<<3)));
        #pragma unroll
        for (int ci = 0; ci < 8; ci++)
          acc[ci][cj] = __builtin_amdgcn_mfma_f32_16x16x32_fp8_fp8(af[ci], bfr, acc[ci][cj], 0,0,0);
      }
    }
  }
  const float sc = 1.0f/256.0f;   // undo (16)^2 scale
  ushortt* dst = Mpart + (size_t)blk*65536;
  #pragma unroll
  for (int ci = 0; ci < 8; ci++){
    #pragma unroll
    for (int cj = 0; cj < 4; cj++){
      int c2 = wn*64 + cj*16 + lr;
      #pragma unroll
      for (int r = 0; r < 4; r++){
        int c1 = wm*128 + ci*16 + g4*4 + r;
        dst[(size_t)c1*256 + c2] = f2bf(acc[ci][cj][r]*sc);
      }
    }
  }
}

__global__ __launch_bounds__(256) void mreduce_kernel(const ushortt* __restrict__ Mpart,
                                                      float* __restrict__ Mm)
{
  int i = blockIdx.x*256 + threadIdx.x;
  float s = 0.f;
  for (int p = 0; p < 256; p++) s += bf2f(Mpart[(size_t)p*65536 + i]);
  Mm[i] = s;
}

// ---------------- fold attn BN into w1f8 (fp8 x64) + b1eff2 (x4) ----------------
__global__ __launch_bounds__(256) void bn2_final(
    const float* __restrict__ Mm, const float* __restrict__ mu_sum,
    const float* __restrict__ aw1,
    const float* __restrict__ ag, const float* __restrict__ abeta,
    u8* __restrict__ w1f8, float* __restrict__ b1eff2)
{
  __shared__ float wrow[256];
  __shared__ float red[8];
  __shared__ float s2s;
  int t = threadIdx.x;
  int ch = blockIdx.x;
  wrow[t] = aw1[(size_t)ch*256 + t];
  __syncthreads();
  float colacc = 0.f;
  for (int r = 0; r < 256; r++) colacc += wrow[r] * Mm[(size_t)r*256 + t];
  float inv = 1.0f/(float)NSAMP;
  float qpart = colacc * wrow[t] * inv;
  float dpart = wrow[t] * mu_sum[t] * inv;
  for (int off=32; off; off>>=1){ qpart += __shfl_xor(qpart, off); dpart += __shfl_xor(dpart, off); }
  if ((t&63)==0){ red[t>>6] = qpart; red[4 + (t>>6)] = dpart; }
  __syncthreads();
  if (t == 0){
    float quad = red[0]+red[1]+red[2]+red[3];
    float dot  = red[4]+red[5]+red[6]+red[7];
    float var = quad - dot*dot;
    float s2 = ag[ch] * rsqrtf(var + 1e-5f);
    b1eff2[ch] = 4.f*(abeta[ch] - dot*s2);   // pre-scaled x4: H = fp8(4*relu(.))
    s2s = s2;
  }
  __syncthreads();
  w1f8[(size_t)ch*256 + t] = f2fp8(64.f*wrow[t]*s2s);
}

// ---------------- GEMM1 (fp8, 128B-pitch LDS, XCD swizzle): H = fp8(relu(.)*4) ----------------
// acc = (16u)*(64w1) = 1024*(u.w1); v4 = acc/256 + b1eff2(x4); H = fp8u(v4)
__global__ __launch_bounds__(512) void gemm1_kernel(
    const u8* __restrict__ U8c, const u8* __restrict__ w1f8,
    const float* __restrict__ b1eff2, u8* __restrict__ H)
{
  __shared__ u8 As8[128*128];   // 16 KB
  __shared__ u8 Bs8[256*128];   // 32 KB (reused as repack)
  int t = threadIdx.x;
  int w = t >> 6, l = t & 63;
  int lr = l & 15, g4 = l >> 4;
  int wm = w >> 2, wn = w & 3;
  int nwg = gridDim.x, cpx = nwg >> 3;
  int logical = (blockIdx.x & 7)*cpx + (blockIdx.x >> 3);
  int mt = logical >> 2, nt = logical & 3;
  int s0 = mt*128, n0 = nt*256;

  f32x4 acc[4][4];
  #pragma unroll
  for (int i=0;i<4;i++) for (int j=0;j<4;j++) acc[i][j] = (f32x4){0.f,0.f,0.f,0.f};

  for (int kt = 0; kt < 2; kt++){
    int k0 = kt*128;
    __syncthreads();
    #pragma unroll
    for (int i = 0; i < 2; i++){
      int c = t + i*512;
      int r = c >> 3, db = (c & 7)*16;
      const u8* src = U8c + (size_t)(s0+r)*256 + k0 + (db ^ ((r&7)<<4));
      gload16(src, As8 + c*16);
    }
    #pragma unroll
    for (int i = 0; i < 4; i++){
      int c = t + i*512;
      int r = c >> 3, db = (c & 7)*16;
      const u8* src = w1f8 + (size_t)(n0+r)*256 + k0 + (db ^ ((r&7)<<4));
      gload16(src, Bs8 + c*16);
    }
    __syncthreads();
    #pragma unroll
    for (int kk = 0; kk < 4; kk++){
      int kb = kk*32 + g4*8;
      long af[4];
      #pragma unroll
      for (int mi = 0; mi < 4; mi++){
        int row = wm*64 + mi*16 + lr;
        af[mi] = *(const long*)(As8 + row*128 + (kb ^ ((row&7)<<4)));
      }
      #pragma unroll
      for (int ni = 0; ni < 4; ni++){
        int row = wn*64 + ni*16 + lr;
        long bfr = *(const long*)(Bs8 + row*128 + (kb ^ ((row&7)<<4)));
        #pragma unroll
        for (int mi = 0; mi < 4; mi++)
          acc[mi][ni] = __builtin_amdgcn_mfma_f32_16x16x32_fp8_fp8(af[mi], bfr, acc[mi][ni], 0,0,0);
      }
    }
  }
  // epilogue: scale 1/256, bias(x4), relu -> fp8 -> LINEAR LDS repack -> coalesced stores
  const float sc1 = 1.0f/256.0f;
  __syncthreads();
  u8* rep = Bs8;                   // 128 x 256 fp8 = 32 KB
  #pragma unroll
  for (int ni = 0; ni < 4; ni++){
    int colc = wn*64 + ni*16 + lr;
    float bias = b1eff2[n0 + colc];
    #pragma unroll
    for (int mi = 0; mi < 4; mi++){
      int sloc = wm*64 + mi*16 + g4*4;
      #pragma unroll
      for (int r = 0; r < 4; r++){
        float v = acc[mi][ni][r]*sc1 + bias;
        v = v > 0.f ? v : 0.f;
        rep[(sloc+r)*256 + colc] = f2fp8u(v);
      }
    }
  }
  __syncthreads();
  #pragma unroll
  for (int i = 0; i < 4; i++){
    int e = t + i*512;
    int row = e >> 4, off = (e & 15)*16;
    *(uint4*)&H[(size_t)(s0+row)*1024 + n0 + off] = *(const uint4*)(rep + e*16);
  }
}

// ---------------- GEMM2 (fp8, 128B-pitch LDS, XCD swizzle): logits + softmax + agg ----------------
__global__ __launch_bounds__(512) void gemm2_kernel(
    const u8* __restrict__ H, const u8* __restrict__ w2f8,
    const float* __restrict__ ab2, const ushortt* __restrict__ val16,
    float* __restrict__ aggT, int s_off)
{
  __shared__ u8 As8[128*128];   // 16 KB
  __shared__ u8 Bs8[256*128];   // 32 KB
  int t = threadIdx.x;
  int w = t >> 6, l = t & 63;
  int lr = l & 15, g4 = l >> 4;
  int wm = w >> 2, wn = w & 3;
  int nwg = gridDim.x, cpx = nwg >> 3;
  int blk = (blockIdx.x & 7)*cpx + (blockIdx.x >> 3);   // match gemm1's H->XCD mapping
  int s0 = blk*128;

  f32x4 acc[4][4];
  #pragma unroll
  for (int i=0;i<4;i++) for (int j=0;j<4;j++) acc[i][j] = (f32x4){0.f,0.f,0.f,0.f};

  for (int kt = 0; kt < 8; kt++){
    int k0 = kt*128;
    __syncthreads();
    #pragma unroll
    for (int i = 0; i < 2; i++){
      int c = t + i*512;
      int r = c >> 3, db = (c & 7)*16;
      const u8* src = H + (size_t)(s0+r)*1024 + k0 + (db ^ ((r&7)<<4));
      gload16(src, As8 + c*16);
    }
    #pragma unroll
    for (int i = 0; i < 4; i++){
      int c = t + i*512;
      int r = c >> 3, db = (c & 7)*16;
      const u8* src = w2f8 + (size_t)r*1024 + k0 + (db ^ ((r&7)<<4));
      gload16(src, Bs8 + c*16);
    }
    __syncthreads();
    #pragma unroll
    for (int kk = 0; kk < 4; kk++){
      int kb = kk*32 + g4*8;
      long af[4];
      #pragma unroll
      for (int mi = 0; mi < 4; mi++){
        int row = wm*64 + mi*16 + lr;
        af[mi] = *(const long*)(As8 + row*128 + (kb ^ ((row&7)<<4)));
      }
      #pragma unroll
      for (int ni = 0; ni < 4; ni++){
        int row = wn*64 + ni*16 + lr;
        long bfr = *(const long*)(Bs8 + row*128 + (kb ^ ((row&7)<<4)));
        #pragma unroll
        for (int mi = 0; mi < 4; mi++)
          acc[mi][ni] = __builtin_amdgcn_mfma_f32_16x16x32_fp8_fp8(af[mi], bfr, acc[mi][ni], 0,0,0);
      }
    }
  }
  const float sc = 1.0f/1024.0f;   // undo W2*256 and H*4
  int ptbase = s_off >> 4;
  #pragma unroll
  for (int mi = 0; mi < 4; mi++){
    int pt = ptbase + blk*8 + wm*4 + mi;
    int sbase = pt*16;
    #pragma unroll
    for (int ni = 0; ni < 4; ni++){
      int d = wn*64 + ni*16 + lr;
      float bias = ab2[d];
      float lg[4];
      #pragma unroll
      for (int r = 0; r < 4; r++) lg[r] = acc[mi][ni][r]*sc + bias;
      float mx = fmaxf(fmaxf(lg[0],lg[1]), fmaxf(lg[2],lg[3]));
      mx = fmaxf(mx, __shfl_xor(mx, 16));
      mx = fmaxf(mx, __shfl_xor(mx, 32));
      float ev[4], ss = 0.f;
      #pragma unroll
      for (int r = 0; r < 4; r++){ ev[r] = __expf(lg[r]-mx); ss += ev[r]; }
      ss += __shfl_xor(ss, 16);
      ss += __shfl_xor(ss, 32);
      float inv = 1.0f/ss;
      float pa = 0.f;
      #pragma unroll
      for (int r = 0; r < 4; r++){
        int s = sbase + g4*4 + r;
        pa += ev[r]*inv*bf2f(val16[(size_t)s*256 + d]);
      }
      pa += __shfl_xor(pa, 16);
      pa += __shfl_xor(pa, 32);
      if (g4 == 0) aggT[(size_t)pt*256 + d] = pa;
    }
  }
}

// ---------------- final: out = end_w @ agg + end_b + valueT ----------------
__global__ __launch_bounds__(256) void final_kernel(
    const float* __restrict__ aggT, const float* __restrict__ endwT,
    const float* __restrict__ endb, const float* __restrict__ valueT,
    float* __restrict__ out)
{
  __shared__ float ags[32*257];
  int t = threadIdx.x;
  int tile = blockIdx.x & 63, b = blockIdx.x >> 6;
  int n0 = tile*32;
  for (int e = t; e < 32*256; e += 256){
    int nn = e >> 8, d = e & 255;
    ags[nn*257 + d] = aggT[(size_t)(b*Nv + n0 + nn)*256 + d];
  }
  __syncthreads();
  int cg = t >> 2, ng = t & 3;
  int co0 = cg*2, nb = ng*8;
  float acc[2][8];
  for (int i=0;i<2;i++){ float bb = endb[co0+i]; for (int j=0;j<8;j++) acc[i][j]=bb; }
  for (int d = 0; d < 256; d++){
    float w0 = endwT[d*128 + co0], w1 = endwT[d*128 + co0 + 1];
    #pragma unroll
    for (int j=0;j<8;j++){
      float av = ags[(nb+j)*257 + d];
      acc[0][j] += w0*av; acc[1][j] += w1*av;
    }
  }
  for (int i=0;i<2;i++){
    for (int j=0;j<8;j++){
      int n = n0 + nb + j;
      size_t o = (size_t)(b*128 + co0 + i)*Nv + n;
      out[o] = acc[i][j] + valueT[(size_t)(b*Nv + n)*128 + co0 + i];
    }
  }
}

extern "C" void kernel_launch(void* const* d_in, const int* in_sizes, int n_in,
                              void* d_out, int out_size, void* d_ws, size_t ws_size,
                              hipStream_t stream)
{
  (void)in_sizes; (void)n_in; (void)out_size;
  const float* pos   = (const float*)d_in[0];
  const float* key   = (const float*)d_in[1];
  const float* query = (const float*)d_in[2];
  const float* mw1   = (const float*)d_in[3];
  const float* mb1   = (const float*)d_in[4];
  const float* mw2   = (const float*)d_in[5];
  const float* mb2   = (const float*)d_in[6];
  const float* mwsc  = (const float*)d_in[7];
  const float* mbsc  = (const float*)d_in[8];
  const float* wk    = (const float*)d_in[9];
  const float* bk    = (const float*)d_in[10];
  const float* wq    = (const float*)d_in[11];
  const float* bq    = (const float*)d_in[12];
  const float* wv    = (const float*)d_in[13];
  const float* bv    = (const float*)d_in[14];
  const float* pw1   = (const float*)d_in[15];
  const float* pg    = (const float*)d_in[17];
  const float* pbeta = (const float*)d_in[18];
  const float* pw2   = (const float*)d_in[19];
  const float* pb2   = (const float*)d_in[20];
  const float* aw1   = (const float*)d_in[21];
  const float* ag    = (const float*)d_in[23];
  const float* abeta = (const float*)d_in[24];
  const float* aw2   = (const float*)d_in[25];
  const float* ab2   = (const float*)d_in[26];
  const float* endw  = (const float*)d_in[27];
  const float* endb  = (const float*)d_in[28];
  float* out = (float*)d_out;

  char* wsb = (char*)d_ws;
  size_t off = 0;
  auto take = [&](size_t bytes)->char*{
    char* p = wsb + off; off += (bytes + 255) & ~(size_t)255; return p;
  };
  float* Mm      = (float*)take(65536*4);
  float* mu_sum  = (float*)take(256*4);     // zeroed
  float* rstat   = (float*)take(12*4);      // zeroed
  size_t zero_bytes = off;
  float* b1eff2  = (float*)take(1024*4);
  float* valueT  = (float*)take((size_t)524288*4);     // [4096 x 128] f32
  float* aggT    = (float*)take((size_t)1048576*4);
  float* endwT   = (float*)take(32768*4);
  int*   idxb    = (int*)take(65536*4);
  ushortt* qT    = (ushortt*)take((size_t)1048576*2);  // bf16 [4096 x 256]
  ushortt* kT    = (ushortt*)take((size_t)1048576*2);
  ushortt* vT    = (ushortt*)take((size_t)1048576*2);
  ushortt* hx16  = (ushortt*)take((size_t)4096*384*2); // [4096 x 384] bf16 (h | x)
  ushortt* wA16  = (ushortt*)take((size_t)768*256*2);
  ushortt* wB16  = (ushortt*)take((size_t)128*384*2);
  ushortt* wv16  = (ushortt*)take((size_t)256*128*2);
  u8*      U8b   = (u8*)take((size_t)16777216);        // fp8 u (x16): gemm1 + mm
  ushortt* val16 = (ushortt*)take((size_t)16777216*2); // bf16 (v + pos_emb)
  ushortt* hposR = (ushortt*)take((size_t)4194304*2);  // bf16 Hpos [65536x64]
  ushortt* Mpart = (ushortt*)take((size_t)256*65536*2);// bf16 M partials (32 MB)
  u8*      w1f8  = (u8*)take((size_t)262144);          // fp8 W1eff (x64)
  u8*      w2f8  = (u8*)take((size_t)262144);          // fp8 W2 (x256)
  ushortt* pw2R  = (ushortt*)take(16384*2);

  // H (fp8) gets whatever is left; chunk the sample dim to fit.
  size_t avail = (ws_size > off) ? (ws_size - off) : 0;
  int nch = 1;
  while (nch < 64 && ((size_t)(NSAMP/nch))*1024 > avail) nch <<= 1;
  int chunk = NSAMP / nch;          // >= 1024, multiple of 128
  u8* H = (u8*)(wsb + off);

  hipMemsetAsync(d_ws, 0, zero_bytes, stream);
  prep_kernel<<<640,256,0,stream>>>(wk,wq,wv,endw,mw1,mw2,mwsc,aw2,pw2,key,query,
                                    wA16,wB16,wv16,endwT,w2f8,pw2R,hx16);
  knn_kernel<<<1024,256,0,stream>>>(pos,idxb);
  gemmA_kernel<<<dim3(32,3),512,0,stream>>>(hx16,wA16,mb1,bk,bq,kT,qT);
  gemmBC_kernel<<<32,512,0,stream>>>(hx16,wB16,mb2,mbsc,wv16,bv,valueT,vT);
  bn1_stats<<<64,256,0,stream>>>(pos,idxb,rstat);
  hpos_kernel<<<2048,256,0,stream>>>(pos,idxb,rstat,pw1,pg,pbeta,hposR);
  gemm0_kernel<<<512,512,0,stream>>>(hposR,pw2R,pb2,idxb,qT,kT,vT,U8b,val16,mu_sum);
  mm_kernel<<<256,512,0,stream>>>(U8b,Mpart);
  mreduce_kernel<<<256,256,0,stream>>>(Mpart,Mm);
  bn2_final<<<1024,256,0,stream>>>(Mm,mu_sum,aw1,ag,abeta,w1f8,b1eff2);
  for (int cc = 0; cc < nch; cc++){
    int s_off = cc*chunk;
    gemm1_kernel<<<(chunk/128)*4,512,0,stream>>>(U8b + (size_t)s_off*256, w1f8, b1eff2, H);
    gemm2_kernel<<<chunk/128,512,0,stream>>>(H, w2f8, ab2, val16, aggT, s_off);
  }
  final_kernel<<<128,256,0,stream>>>(aggT,endwT,endb,valueT,out);
}